// Round 12
// baseline (143.749 us; speedup 1.0000x reference)
//
#include <hip/hip_runtime.h>
#include <hip/hip_bf16.h>

#define Bsz 64
#define Wln 512
#define Hd  1024
#define Vc  32000

typedef short v8s __attribute__((ext_vector_type(8)));
typedef float f32x4 __attribute__((ext_vector_type(4)));

__device__ inline unsigned short f2b(float f) {  // round to bf16
  union { float f; unsigned u; } v; v.f = f;
  return (unsigned short)((v.u + 0x8000u) >> 16);
}
__device__ inline float wave_sum(float v) {
  #pragma unroll
  for (int o = 32; o; o >>= 1) v += __shfl_down(v, o);
  return v;
}
__device__ inline float wave_max(float v) {
  #pragma unroll
  for (int o = 32; o; o >>= 1) v = fmaxf(v, __shfl_down(v, o));
  return v;
}
__device__ inline float wave_sum_all(float v) {
  #pragma unroll
  for (int o = 32; o; o >>= 1) v += __shfl_xor(v, o);
  return v;
}
__device__ inline float wave_max_all(float v) {
  #pragma unroll
  for (int o = 32; o; o >>= 1) v = fmaxf(v, __shfl_xor(v, o));
  return v;
}
__device__ inline float sigm(float x) { return 1.f / (1.f + expf(-x)); }

__device__ inline v8s cvt_frag(float4 x0, float4 x1) {
  v8s r;
  r[0] = (short)f2b(x0.x); r[1] = (short)f2b(x0.y);
  r[2] = (short)f2b(x0.z); r[3] = (short)f2b(x0.w);
  r[4] = (short)f2b(x1.x); r[5] = (short)f2b(x1.y);
  r[6] = (short)f2b(x1.z); r[7] = (short)f2b(x1.w);
  return r;
}

// stage 64 x 1024 f32 (row stride sA, optional elementwise-add Ab) -> LDS bf16, swizzled
__device__ inline void stage_A(const float* __restrict__ A, const float* __restrict__ Ab,
                               int sA, char* pool, int tid) {
  #pragma unroll
  for (int it = 0; it < 16; ++it) {
    int idx = it * 512 + tid;
    int row = idx >> 7, ch = idx & 127;
    const float* src = A + (size_t)row * sA + ch * 8;
    float4 x0 = *(const float4*)src;
    float4 x1 = *(const float4*)(src + 4);
    if (Ab) {
      const float* s2 = Ab + (size_t)row * sA + ch * 8;
      float4 y0 = *(const float4*)s2;
      float4 y1 = *(const float4*)(s2 + 4);
      x0.x += y0.x; x0.y += y0.y; x0.z += y0.z; x0.w += y0.w;
      x1.x += y1.x; x1.y += y1.y; x1.z += y1.z; x1.w += y1.w;
    }
    *(v8s*)(pool + row * 2048 + ((ch * 16) ^ ((row & 7) << 4))) = cvt_frag(x0, x1);
  }
}

// ---- fused: attention scores (blocks 0..8191) + s_att/emb gather (8192..8255) ----
__global__ __launch_bounds__(256) void k_scores_satt(
    const float* __restrict__ enc, const float* __restrict__ att_w,
    const float* __restrict__ h0, const float* __restrict__ c0,
    const float* __restrict__ att_b, const int* __restrict__ input,
    const float* __restrict__ emb,
    float* __restrict__ scores, float* __restrict__ s_att,
    float* __restrict__ cat)
{
  __shared__ float red[4];
  int t = threadIdx.x;
  if (blockIdx.x < 8192) {
    int row = blockIdx.x * 4 + (t >> 6);
    int lane = t & 63;
    const float* p = enc + (size_t)row * Hd + lane * 16;
    const float* w = att_w + lane * 16;
    float s = 0.f;
    #pragma unroll
    for (int c = 0; c < 4; ++c) {
      float4 e = *(const float4*)(p + c * 4);
      float4 ww = *(const float4*)(w + c * 4);
      s += e.x * ww.x + e.y * ww.y + e.z * ww.z + e.w * ww.w;
    }
    s = wave_sum(s);
    if (lane == 0) scores[row] = s;     // s_att added in ctx softmax
  } else {
    int b = blockIdx.x - 8192;
    int idx = input[b];
    for (int j = t; j < Hd; j += 256)
      cat[b * 2 * Hd + Hd + j] = emb[(size_t)idx * Hd + j];
    size_t base = (size_t)(Bsz + b) * Hd;
    float s = 0.f;
    for (int j = t; j < Hd; j += 256)
      s += h0[base + j] * c0[base + j] * att_w[Hd + j];
    s = wave_sum(s);
    if ((t & 63) == 0) red[t >> 6] = s;
    __syncthreads();
    if (t == 0) s_att[b] = red[0] + red[1] + red[2] + red[3] + att_b[0];
  }
}

// ---- merged softmax+ctx: block = (b, 256-col quarter); small LDS, high occ ----
__global__ __launch_bounds__(512) void k_ctx(
    const float* __restrict__ scores, const float* __restrict__ s_att,
    const float* __restrict__ enc, float* __restrict__ cat)
{
  __shared__ float w_sh[Wln];
  __shared__ float part[8][256];
  __shared__ float redA[8], redB[8];
  int b = blockIdx.x >> 2, qtr = blockIdx.x & 3;
  int tid = threadIdx.x, w = tid >> 6, lane = tid & 63;
  float sa = s_att[b];
  const float* sr = scores + b * Wln;
  float v = (tid == 0) ? 0.f : sr[tid - 1] + sa;
  float m = wave_max(v);
  if (lane == 0) redA[w] = m;
  __syncthreads();
  float M = redA[0];
  #pragma unroll
  for (int i = 1; i < 8; ++i) M = fmaxf(M, redA[i]);
  float e = expf(v - M);
  float s = wave_sum(e);
  if (lane == 0) redB[w] = s;
  __syncthreads();
  float S = redB[0];
  #pragma unroll
  for (int i = 1; i < 8; ++i) S += redB[i];
  w_sh[tid] = e / S;
  __syncthreads();

  const float* pb = enc + (size_t)b * Wln * Hd + qtr * 256 + lane * 4;
  float a0 = 0, a1 = 0, a2 = 0, a3 = 0;
  #pragma unroll 4
  for (int i = 0; i < 64; ++i) {
    int row = w * 64 + i;
    float4 ev = *(const float4*)(pb + (size_t)row * Hd);
    float wi = w_sh[row];
    a0 += wi * ev.x; a1 += wi * ev.y; a2 += wi * ev.z; a3 += wi * ev.w;
  }
  part[w][lane * 4 + 0] = a0; part[w][lane * 4 + 1] = a1;
  part[w][lane * 4 + 2] = a2; part[w][lane * 4 + 3] = a3;
  __syncthreads();
  if (tid < 256) {
    float s2 = 0.f;
    #pragma unroll
    for (int ww = 0; ww < 8; ++ww) s2 += part[ww][tid];
    cat[b * 2 * Hd + qtr * 256 + tid] = s2;
  }
}

// ---- input half-GEMM: 128 blocks; blk<64: x1 = ctx@inW[:, :1024]^T + inb;
//      blk>=64: x2 = emb@inW[:, 1024:]^T. NS=1, KS=8, single phase. ----
__global__ __launch_bounds__(512) void k_input_gemm(
    const float* __restrict__ cat, const float* __restrict__ inW,
    const float* __restrict__ inb, float* __restrict__ x1, float* __restrict__ x2)
{
  __shared__ __align__(16) char pool[131072];
  const int tid = threadIdx.x;
  const int w = tid >> 6, lane = tid & 63;
  const int r = lane & 15, q = lane >> 4;
  const int kh = w;                       // KS=8, KSL=128
  const int half = (blockIdx.x >= 64);
  const int n0 = (blockIdx.x & 63) * 16;
  const float* A = cat + half * 1024;
  const float* B = inW + half * 1024;
  float* out = half ? x2 : x1;

  const float* bp = B + (size_t)(n0 + r) * 2048 + kh * 128 + q * 8;
  float4 breg[4][2];
  #pragma unroll
  for (int kk = 0; kk < 4; ++kk) {
    breg[kk][0] = *(const float4*)(bp + kk * 32);
    breg[kk][1] = *(const float4*)(bp + kk * 32 + 4);
  }
  stage_A(A, nullptr, 2048, pool, tid);
  __syncthreads();

  f32x4 acc[4] = {{0,0,0,0},{0,0,0,0},{0,0,0,0},{0,0,0,0}};
  const int swz = (r & 7) << 4;
  #pragma unroll
  for (int kk = 0; kk < 4; ++kk) {
    v8s bf = cvt_frag(breg[kk][0], breg[kk][1]);
    int cb = ((kh * 128 + kk * 32 + q * 8) * 2) ^ swz;
    #pragma unroll
    for (int m = 0; m < 4; ++m) {
      v8s af = *(const v8s*)(pool + (m * 16 + r) * 2048 + cb);
      acc[m] = __builtin_amdgcn_mfma_f32_16x16x32_bf16(af, bf, acc[m], 0, 0, 0);
    }
  }
  __syncthreads();

  float (*red)[64][17] = (float(*)[64][17])pool;
  #pragma unroll
  for (int m = 0; m < 4; ++m)
    #pragma unroll
    for (int rr = 0; rr < 4; ++rr)
      red[w][lane][m * 4 + rr] = acc[m][rr];
  __syncthreads();

  #pragma unroll
  for (int it = 0; it < 2; ++it) {
    int e = it * 512 + tid;                // [0,1024): 64 rows x 16 cols
    int cc = e & 15, rowi = e >> 4;
    int idx = ((rowi >> 4) << 2) + (rowi & 3);
    int le  = (((rowi >> 2) & 3) << 4) + cc;
    float s = 0.f;
    #pragma unroll
    for (int j = 0; j < 8; ++j) s += red[j][le][idx];
    float bb = half ? 0.f : inb[n0 + cc];
    out[(size_t)rowi * Hd + n0 + cc] = s + bb;
  }
}

// ---- fused gate GEMM + LSTM: 256 blocks x 16 cols (4 j x 4 gates) ----
// Phase 0 stages xA(+xAb); phase 1 stages hA; acc carries the sum.
__global__ __launch_bounds__(512) void k_gate_lstm(
    const float* __restrict__ xA, const float* __restrict__ xAb,
    const float* __restrict__ hA,
    const float* __restrict__ W_ih, const float* __restrict__ W_hh,
    const float* __restrict__ b_ih, const float* __restrict__ b_hh,
    const float* __restrict__ c0,
    float* __restrict__ out_h, float* __restrict__ out_c)
{
  __shared__ __align__(16) char pool[131072];
  const int tid = threadIdx.x;
  const int w = tid >> 6, lane = tid & 63;
  const int r = lane & 15, q = lane >> 4;
  const int kh = w;                        // NS=1: KS=8, KSL=128 per phase
  const int gate = r >> 2, jl = r & 3;
  const size_t Brow = (size_t)gate * Hd + blockIdx.x * 4 + jl;

  f32x4 acc[4] = {{0,0,0,0},{0,0,0,0},{0,0,0,0},{0,0,0,0}};
  const float* Amat[2] = { xA, hA };
  const float* Abm[2]  = { xAb, nullptr };
  const float* Wmat[2] = { W_ih, W_hh };
  #pragma unroll
  for (int p = 0; p < 2; ++p) {
    const float* bp = Wmat[p] + Brow * Hd + kh * 128 + q * 8;
    float4 breg[4][2];
    #pragma unroll
    for (int kk = 0; kk < 4; ++kk) {
      breg[kk][0] = *(const float4*)(bp + kk * 32);
      breg[kk][1] = *(const float4*)(bp + kk * 32 + 4);
    }
    stage_A(Amat[p], Abm[p], Hd, pool, tid);
    __syncthreads();
    const int swz = (r & 7) << 4;
    #pragma unroll
    for (int kk = 0; kk < 4; ++kk) {
      v8s bf = cvt_frag(breg[kk][0], breg[kk][1]);
      int cb = ((kh * 128 + kk * 32 + q * 8) * 2) ^ swz;
      #pragma unroll
      for (int m = 0; m < 4; ++m) {
        v8s af = *(const v8s*)(pool + (m * 16 + r) * 2048 + cb);
        acc[m] = __builtin_amdgcn_mfma_f32_16x16x32_bf16(af, bf, acc[m], 0, 0, 0);
      }
    }
    __syncthreads();
  }

  float (*red)[64][17] = (float(*)[64][17])pool;
  #pragma unroll
  for (int m = 0; m < 4; ++m)
    #pragma unroll
    for (int rr = 0; rr < 4; ++rr)
      red[w][lane][m * 4 + rr] = acc[m][rr];
  __syncthreads();

  // epilogue: thread = (b, jl2) for tid<256; gather 4 gates, run LSTM
  if (tid < 256) {
    int b = tid >> 2, jl2 = tid & 3;
    int jg = blockIdx.x * 4 + jl2;
    float gv[4];
    #pragma unroll
    for (int g2 = 0; g2 < 4; ++g2) {
      int cc = g2 * 4 + jl2;
      int idx = ((b >> 4) << 2) + (b & 3);
      int le  = (((b >> 2) & 3) << 4) + cc;
      float s = 0.f;
      #pragma unroll
      for (int j = 0; j < 8; ++j) s += red[j][le][idx];
      gv[g2] = s + b_ih[(size_t)g2 * Hd + jg] + b_hh[(size_t)g2 * Hd + jg];
    }
    float c = sigm(gv[1]) * c0[(size_t)b * Hd + jg] + sigm(gv[0]) * tanhf(gv[2]);
    float h = sigm(gv[3]) * tanhf(c);
    out_h[(size_t)b * Hd + jg] = h;
    out_c[(size_t)b * Hd + jg] = c;
  }
}

// ---- logits GEMM + fused log-softmax partials: NS=4, 500 blocks ----
__global__ __launch_bounds__(512) void k_logits(
    const float* __restrict__ A, const float* __restrict__ B,
    const float* __restrict__ bias, float* __restrict__ out,
    float* __restrict__ pm, float* __restrict__ ps)
{
  __shared__ __align__(16) char pool[131072];
  const int tid = threadIdx.x;
  const int w = tid >> 6, lane = tid & 63;
  const int r = lane & 15, q = lane >> 4;
  const int nsub = w & 3, kh = w >> 2;    // NS=4: KS=2, KSL=512
  const int n0 = blockIdx.x * 64;

  const float* bp = B + (size_t)(n0 + nsub * 16 + r) * Hd + kh * 512 + q * 8;
  float4 breg[16][2];
  #pragma unroll
  for (int kk = 0; kk < 16; ++kk) {
    breg[kk][0] = *(const float4*)(bp + kk * 32);
    breg[kk][1] = *(const float4*)(bp + kk * 32 + 4);
  }
  stage_A(A, nullptr, Hd, pool, tid);
  __syncthreads();

  f32x4 acc[4] = {{0,0,0,0},{0,0,0,0},{0,0,0,0},{0,0,0,0}};
  const int swz = (r & 7) << 4;
  #pragma unroll
  for (int kk = 0; kk < 16; ++kk) {
    v8s bf = cvt_frag(breg[kk][0], breg[kk][1]);
    int cb = ((kh * 512 + kk * 32 + q * 8) * 2) ^ swz;
    #pragma unroll
    for (int m = 0; m < 4; ++m) {
      v8s af = *(const v8s*)(pool + (m * 16 + r) * 2048 + cb);
      acc[m] = __builtin_amdgcn_mfma_f32_16x16x32_bf16(af, bf, acc[m], 0, 0, 0);
    }
  }
  __syncthreads();

  float (*red)[64][17] = (float(*)[64][17])pool;
  #pragma unroll
  for (int m = 0; m < 4; ++m)
    #pragma unroll
    for (int rr = 0; rr < 4; ++rr)
      red[w][lane][m * 4 + rr] = acc[m][rr];
  __syncthreads();

  #pragma unroll
  for (int it = 0; it < 8; ++it) {
    int e = it * 512 + tid;               // rowi = it*8 + wave; lane = cc
    int cc = e & 63, rowi = e >> 6;
    int ns2 = cc >> 4, lo = cc & 15;
    int idx = ((rowi >> 4) << 2) + (rowi & 3);
    int le  = (((rowi >> 2) & 3) << 4) + lo;
    float val = red[ns2][le][idx] + red[ns2 + 4][le][idx] + bias[n0 + cc];
    out[(size_t)rowi * Vc + n0 + cc] = val;
    // fused per-tile log-softmax partial: one wave holds one row's 64 cols
    float wm = wave_max_all(val);
    float we = wave_sum_all(expf(val - wm));
    if (cc == 0) { pm[blockIdx.x * 64 + rowi] = wm; ps[blockIdx.x * 64 + rowi] = we; }
  }
}

// ---- combine 500 partials per row, subtract lse; block = (b, 8000-col chunk) ----
__global__ __launch_bounds__(512) void k_lsm_sub(
    float* __restrict__ lg, const float* __restrict__ pm, const float* __restrict__ ps)
{
  __shared__ float redA[8], redB[8];
  int b = blockIdx.x >> 2, qc = blockIdx.x & 3;
  int tid = threadIdx.x, w = tid >> 6, lane = tid & 63;
  float m = -1e30f;
  for (int j = tid; j < 500; j += 512) m = fmaxf(m, pm[j * 64 + b]);
  m = wave_max(m);
  if (lane == 0) redA[w] = m;
  __syncthreads();
  float M = redA[0];
  #pragma unroll
  for (int i = 1; i < 8; ++i) M = fmaxf(M, redA[i]);
  float s = 0.f;
  for (int j = tid; j < 500; j += 512) s += ps[j * 64 + b] * expf(pm[j * 64 + b] - M);
  s = wave_sum(s);
  if (lane == 0) redB[w] = s;
  __syncthreads();
  float S = redB[0];
  #pragma unroll
  for (int i = 1; i < 8; ++i) S += redB[i];
  float lse = M + logf(S);
  float* row = lg + (size_t)b * Vc + qc * 8000;
  for (int j = tid * 4; j < 8000; j += 2048) {
    float4 v = *(const float4*)(row + j);
    v.x -= lse; v.y -= lse; v.z -= lse; v.w -= lse;
    *(float4*)(row + j) = v;
  }
}

extern "C" void kernel_launch(void* const* d_in, const int* in_sizes, int n_in,
                              void* d_out, int out_size, void* d_ws, size_t ws_size,
                              hipStream_t stream)
{
  const int*   input = (const int*)d_in[0];
  const float* h0    = (const float*)d_in[1];
  const float* c0    = (const float*)d_in[2];
  const float* enc   = (const float*)d_in[3];
  const float* emb   = (const float*)d_in[4];
  const float* W_ih0 = (const float*)d_in[5];
  const float* W_hh0 = (const float*)d_in[6];
  const float* b_ih0 = (const float*)d_in[7];
  const float* b_hh0 = (const float*)d_in[8];
  const float* W_ih1 = (const float*)d_in[9];
  const float* W_hh1 = (const float*)d_in[10];
  const float* b_ih1 = (const float*)d_in[11];
  const float* b_hh1 = (const float*)d_in[12];
  const float* att_w = (const float*)d_in[13];
  const float* att_b = (const float*)d_in[14];
  const float* inW   = (const float*)d_in[15];
  const float* inb   = (const float*)d_in[16];
  const float* outW  = (const float*)d_in[17];
  const float* outb  = (const float*)d_in[18];
  float* out = (float*)d_out;

  char* ws = (char*)d_ws;
  float* cat    = (float*)(ws + 0);          // 64x2048 [ctx | emb]
  float* x1     = (float*)(ws + 524288);     // 64x1024
  float* x2     = (float*)(ws + 786432);     // 64x1024
  float* scores = (float*)(ws + 1048576);    // 64x512
  float* s_att  = (float*)(ws + 1179648);    // 64
  float* pm     = (float*)(ws + 1180672);    // 500x64
  float* ps     = (float*)(ws + 1310720);    // 500x64

  float* out_h = out + (size_t)Bsz * Vc;     // [2,B,H]
  float* out_c = out_h + 2 * Bsz * Hd;       // [2,B,H]
  float* h1 = out_h;
  float* h2 = out_h + Bsz * Hd;

  k_scores_satt<<<8256, 256, 0, stream>>>(enc, att_w, h0, c0, att_b, input, emb,
                                          scores, s_att, cat);
  k_ctx<<<Bsz * 4, 512, 0, stream>>>(scores, s_att, enc, cat);
  k_input_gemm<<<128, 512, 0, stream>>>(cat, inW, inb, x1, x2);
  k_gate_lstm<<<256, 512, 0, stream>>>(x1, x2, h0, W_ih0, W_hh0, b_ih0, b_hh0,
                                       c0, h1, out_c);
  k_gate_lstm<<<256, 512, 0, stream>>>(h1, nullptr, h0 + (size_t)Bsz * Hd,
                                       W_ih1, W_hh1, b_ih1, b_hh1,
                                       c0 + (size_t)Bsz * Hd, h2, out_c + Bsz * Hd);
  k_logits<<<500, 512, 0, stream>>>(h2, outW, outb, out, pm, ps);
  k_lsm_sub<<<256, 512, 0, stream>>>(out, pm, ps);
}